// Round 2
// baseline (211.513 us; speedup 1.0000x reference)
//
#include <hip/hip_runtime.h>

typedef __bf16 bf16_t;
typedef bf16_t bf16x8 __attribute__((ext_vector_type(8)));
typedef float f32x4 __attribute__((ext_vector_type(4)));

#define NB 8
#define TT 2048
#define DIN 1024
#define HH 64
#define MM (NB * TT)

__device__ __forceinline__ unsigned short f2bf(float f) {
    unsigned int u = __float_as_uint(f);
    u += 0x7fffu + ((u >> 16) & 1u);   // round-to-nearest-even
    return (unsigned short)(u >> 16);
}

// ------------------------------------------------------------------
// Dtype probe: scan first 4096 u32 words of x. For bf16-packed data,
// (u>>7)&0xFF is the LOW bf16's exponent (~[117,133] for N(0,1) data,
// ~100% in range). For fp32 data those bits are random mantissa bits
// (~20% in range). flag=1 -> inputs/outputs are fp32.
// ------------------------------------------------------------------
__global__ void detect_kernel(const unsigned int* __restrict__ xw,
                              int* __restrict__ flag) {
    __shared__ int cnt_s[4];
    int tid = threadIdx.x;
    int c = 0;
#pragma unroll
    for (int i = 0; i < 16; ++i) {
        unsigned int u = xw[tid * 16 + i];
        unsigned int e = (u >> 7) & 0xFFu;
        c += (e >= 100u && e <= 150u) ? 1 : 0;
    }
#pragma unroll
    for (int off = 1; off < 64; off <<= 1) c += __shfl_xor(c, off);
    if ((tid & 63) == 0) cnt_s[tid >> 6] = c;
    __syncthreads();
    if (tid == 0) {
        int tot = cnt_s[0] + cnt_s[1] + cnt_s[2] + cnt_s[3];
        *flag = (tot < 3000) ? 1 : 0;
    }
}

// ------------------------------------------------------------------
// Wt[w][n][k] = W_w[k][n], always stored as bf16.
// ------------------------------------------------------------------
__global__ void transpose_w_kernel(const void* __restrict__ Wq,
                                   const void* __restrict__ Wk,
                                   const void* __restrict__ Wv,
                                   unsigned short* __restrict__ Wt,
                                   const int* __restrict__ flagp) {
    const int isf32 = *flagp;
    int idx = blockIdx.x * 256 + threadIdx.x;   // 0..196607
    int w = idx >> 16;
    int rem = idx & 65535;
    int k = rem >> 6;
    int n = rem & 63;
    const void* W = (w == 0) ? Wq : (w == 1) ? Wk : Wv;
    unsigned short v;
    if (isf32) v = f2bf(((const float*)W)[rem]);
    else       v = ((const unsigned short*)W)[rem];
    Wt[(size_t)w * 65536 + (size_t)n * 1024 + k] = v;
}

// ------------------------------------------------------------------
// Projection GEMM: out[m][n] = sum_k x[m][k] * W[k][n]
// grid (M/128, 3), 256 threads (4 waves), 16x16x32 bf16 MFMA.
// ------------------------------------------------------------------
__global__ __launch_bounds__(256) void proj_kernel(
    const void* __restrict__ xraw,
    const unsigned short* __restrict__ Wt,
    unsigned short* __restrict__ qbuf,
    unsigned short* __restrict__ kbuf,
    unsigned short* __restrict__ vtbuf,
    const int* __restrict__ flagp) {

    __shared__ __align__(16) unsigned short xs[128][72];   // +8 pad
    __shared__ __align__(16) unsigned short wts[64][72];

    const int isf32 = *flagp;
    const int tid  = threadIdx.x;
    const int w    = blockIdx.y;
    const int m0   = blockIdx.x * 128;
    const int wave = tid >> 6;
    const int lane = tid & 63;
    const int quad = lane >> 4;
    const int l15  = lane & 15;

    f32x4 acc[2][4];
#pragma unroll
    for (int r = 0; r < 2; ++r)
#pragma unroll
        for (int c = 0; c < 4; ++c)
            acc[r][c] = (f32x4){0.f, 0.f, 0.f, 0.f};

    const int xr = tid >> 1;          // 0..127
    const int xc = (tid & 1) * 32;    // 0,32
    const int wn = tid >> 2;          // 0..63
    const int wc = (tid & 3) * 16;    // 0,16,32,48

    const unsigned short* xb = (const unsigned short*)xraw;
    const float*          xf = (const float*)xraw;

    for (int k0 = 0; k0 < DIN; k0 += 64) {
        if (isf32) {
            const float4* gx = (const float4*)(xf + (size_t)(m0 + xr) * DIN + k0 + xc);
#pragma unroll
            for (int j = 0; j < 8; ++j) {
                float4 f = gx[j];
                unsigned short* p = &xs[xr][xc + j * 4];
                p[0] = f2bf(f.x); p[1] = f2bf(f.y);
                p[2] = f2bf(f.z); p[3] = f2bf(f.w);
            }
        } else {
            const uint4* gx = (const uint4*)(xb + (size_t)(m0 + xr) * DIN + k0 + xc);
            uint4 v0 = gx[0], v1 = gx[1], v2 = gx[2], v3 = gx[3];
            *(uint4*)&xs[xr][xc + 0]  = v0;
            *(uint4*)&xs[xr][xc + 8]  = v1;
            *(uint4*)&xs[xr][xc + 16] = v2;
            *(uint4*)&xs[xr][xc + 24] = v3;
        }

        const uint4* gw = (const uint4*)(Wt + (size_t)w * 65536 + (size_t)wn * 1024 + k0 + wc);
        uint4 u0 = gw[0], u1 = gw[1];
        *(uint4*)&wts[wn][wc + 0] = u0;
        *(uint4*)&wts[wn][wc + 8] = u1;
        __syncthreads();

#pragma unroll
        for (int ks = 0; ks < 2; ++ks) {
            bf16x8 a0 = *(const bf16x8*)&xs[wave * 32 + 0  + l15][ks * 32 + quad * 8];
            bf16x8 a1 = *(const bf16x8*)&xs[wave * 32 + 16 + l15][ks * 32 + quad * 8];
#pragma unroll
            for (int c = 0; c < 4; ++c) {
                bf16x8 bb = *(const bf16x8*)&wts[c * 16 + l15][ks * 32 + quad * 8];
                acc[0][c] = __builtin_amdgcn_mfma_f32_16x16x32_bf16(a0, bb, acc[0][c], 0, 0, 0);
                acc[1][c] = __builtin_amdgcn_mfma_f32_16x16x32_bf16(a1, bb, acc[1][c], 0, 0, 0);
            }
        }
        __syncthreads();
    }

    // epilogue: D[row=quad*4+reg][col=l15]
#pragma unroll
    for (int r = 0; r < 2; ++r)
#pragma unroll
        for (int c = 0; c < 4; ++c)
#pragma unroll
            for (int reg = 0; reg < 4; ++reg) {
                int m = m0 + wave * 32 + r * 16 + quad * 4 + reg;
                int n = c * 16 + l15;
                unsigned short bv = f2bf(acc[r][c][reg]);
                if (w == 0)      qbuf[(size_t)m * HH + n] = bv;
                else if (w == 1) kbuf[(size_t)m * HH + n] = bv;
                else {
                    int bb = m >> 11, t = m & 2047;
                    vtbuf[((size_t)bb * HH + n) * TT + t] = bv;
                }
            }
}

// ------------------------------------------------------------------
// Flash attention: rows = k-proj, cols = q-proj, causal, fp32 softmax.
// grid (T/64, B), 256 threads; wave owns 16 rows x 64 head-cols.
// ------------------------------------------------------------------
__global__ __launch_bounds__(256) void attn_kernel(
    const unsigned short* __restrict__ rowbuf,  // k-proj [b][t][h]
    const unsigned short* __restrict__ colbuf,  // q-proj [b][s][h]
    const unsigned short* __restrict__ vtbuf,   // [b][h][s]
    void* __restrict__ outraw,
    const int* __restrict__ flagp) {

    __shared__ __align__(16) unsigned short Qr_s[64][72];
    __shared__ __align__(16) unsigned short Kc_s[64][72];
    __shared__ __align__(16) unsigned short Vt_s[64][72];
    __shared__ __align__(16) unsigned short P_s[4][16][72];

    const int isf32 = *flagp;
    const int tid   = threadIdx.x;
    const int ttile = blockIdx.x;
    const int b     = blockIdx.y;
    const int t0    = ttile * 64;
    const int wave  = tid >> 6;
    const int lane  = tid & 63;
    const int quad  = lane >> 4;
    const int l15   = lane & 15;

    const int sr = tid >> 2;         // 0..63
    const int sc = (tid & 3) * 16;   // 0,16,32,48

    {
        const uint4* g = (const uint4*)(rowbuf + ((size_t)b * TT + t0 + sr) * HH + sc);
        *(uint4*)&Qr_s[sr][sc + 0] = g[0];
        *(uint4*)&Qr_s[sr][sc + 8] = g[1];
    }

    f32x4 o[4];
#pragma unroll
    for (int c = 0; c < 4; ++c) o[c] = (f32x4){0.f, 0.f, 0.f, 0.f};
    float mx[4], lsum[4];
#pragma unroll
    for (int r = 0; r < 4; ++r) { mx[r] = -30000.f; lsum[r] = 0.f; }

    const float SCL = 0.125f * 1.4426950408889634f;  // head^-0.5 * log2(e)

    for (int st = 0; st <= ttile; ++st) {
        const int s0 = st * 64;
        {
            const uint4* gk = (const uint4*)(colbuf + ((size_t)b * TT + s0 + sr) * HH + sc);
            uint4 k0 = gk[0], k1 = gk[1];
            const uint4* gv = (const uint4*)(vtbuf + ((size_t)b * HH + sr) * TT + s0 + sc);
            uint4 q0 = gv[0], q1 = gv[1];
            *(uint4*)&Kc_s[sr][sc + 0] = k0;
            *(uint4*)&Kc_s[sr][sc + 8] = k1;
            *(uint4*)&Vt_s[sr][sc + 0] = q0;
            *(uint4*)&Vt_s[sr][sc + 8] = q1;
        }
        __syncthreads();

        // S = Qr * Kc^T
        f32x4 scf[4];
#pragma unroll
        for (int c = 0; c < 4; ++c) scf[c] = (f32x4){0.f, 0.f, 0.f, 0.f};
#pragma unroll
        for (int ks = 0; ks < 2; ++ks) {
            bf16x8 a = *(const bf16x8*)&Qr_s[wave * 16 + l15][ks * 32 + quad * 8];
#pragma unroll
            for (int c = 0; c < 4; ++c) {
                bf16x8 bb = *(const bf16x8*)&Kc_s[c * 16 + l15][ks * 32 + quad * 8];
                scf[c] = __builtin_amdgcn_mfma_f32_16x16x32_bf16(a, bb, scf[c], 0, 0, 0);
            }
        }

        const bool diag = (st == ttile);
#pragma unroll
        for (int r = 0; r < 4; ++r) {
            const int tg = t0 + wave * 16 + quad * 4 + r;
            float xv[4];
#pragma unroll
            for (int c = 0; c < 4; ++c) {
                float v = scf[c][r] * SCL;
                if (diag && (s0 + c * 16 + l15) > tg) v = -30000.f;
                xv[c] = v;
            }
            float rm = fmaxf(fmaxf(xv[0], xv[1]), fmaxf(xv[2], xv[3]));
#pragma unroll
            for (int off = 1; off < 16; off <<= 1) rm = fmaxf(rm, __shfl_xor(rm, off));
            float mnew = fmaxf(mx[r], rm);
            float alpha = exp2f(mx[r] - mnew);
            float rs = 0.f;
#pragma unroll
            for (int c = 0; c < 4; ++c) {
                float p = exp2f(xv[c] - mnew);
                P_s[wave][quad * 4 + r][c * 16 + l15] = f2bf(p);
                rs += p;
            }
#pragma unroll
            for (int off = 1; off < 16; off <<= 1) rs += __shfl_xor(rs, off);
            lsum[r] = lsum[r] * alpha + rs;
            mx[r] = mnew;
#pragma unroll
            for (int c = 0; c < 4; ++c) o[c][r] = o[c][r] * alpha;
        }
        __syncthreads();

        // O += P * V
#pragma unroll
        for (int ks = 0; ks < 2; ++ks) {
            bf16x8 ap = *(const bf16x8*)&P_s[wave][l15][ks * 32 + quad * 8];
#pragma unroll
            for (int c = 0; c < 4; ++c) {
                bf16x8 bv = *(const bf16x8*)&Vt_s[c * 16 + l15][ks * 32 + quad * 8];
                o[c] = __builtin_amdgcn_mfma_f32_16x16x32_bf16(ap, bv, o[c], 0, 0, 0);
            }
        }
        __syncthreads();
    }

    unsigned short* outb = (unsigned short*)outraw;
    float*          outf = (float*)outraw;
#pragma unroll
    for (int c = 0; c < 4; ++c)
#pragma unroll
        for (int r = 0; r < 4; ++r) {
            int t = t0 + wave * 16 + quad * 4 + r;
            size_t idx = ((size_t)b * TT + t) * HH + c * 16 + l15;
            float val = o[c][r] / lsum[r];
            if (isf32) outf[idx] = val;
            else       outb[idx] = f2bf(val);
        }
}

extern "C" void kernel_launch(void* const* d_in, const int* in_sizes, int n_in,
                              void* d_out, int out_size, void* d_ws, size_t ws_size,
                              hipStream_t stream) {
    const void* x  = d_in[0];
    const void* Wq = d_in[1];
    const void* Wk = d_in[2];
    const void* Wv = d_in[3];
    unsigned short* ws = (unsigned short*)d_ws;

    unsigned short* qbuf  = ws;                          // q-proj (cols)
    unsigned short* kbuf  = ws + (size_t)MM * HH;        // k-proj (rows)
    unsigned short* vtbuf = ws + (size_t)2 * MM * HH;    // V^T [b][h][t]
    unsigned short* wtbuf = ws + (size_t)3 * MM * HH;    // Wt [3][64][1024]
    int* flagp = (int*)(ws + (size_t)3 * MM * HH + 3 * 65536);

    hipLaunchKernelGGL(detect_kernel, dim3(1), dim3(256), 0, stream,
                       (const unsigned int*)x, flagp);
    hipLaunchKernelGGL(transpose_w_kernel, dim3(768), dim3(256), 0, stream,
                       Wq, Wk, Wv, wtbuf, flagp);
    hipLaunchKernelGGL(proj_kernel, dim3(128, 3), dim3(256), 0, stream,
                       x, wtbuf, qbuf, kbuf, vtbuf, flagp);
    hipLaunchKernelGGL(attn_kernel, dim3(32, 8), dim3(256), 0, stream,
                       kbuf, qbuf, vtbuf, d_out, flagp);
}

// Round 3
// 160.258 us; speedup vs baseline: 1.3198x; 1.3198x over previous
//
#include <hip/hip_runtime.h>

typedef __bf16 bf16_t;
typedef bf16_t bf16x8 __attribute__((ext_vector_type(8)));
typedef float f32x4 __attribute__((ext_vector_type(4)));

#define NB 8
#define TT 2048
#define DIN 1024
#define HH 64
#define MM (NB * TT)

__device__ __forceinline__ unsigned short f2bf(float f) {
    unsigned int u = __float_as_uint(f);
    u += 0x7fffu + ((u >> 16) & 1u);   // round-to-nearest-even
    return (unsigned short)(u >> 16);
}

// Per-block dtype probe (see R1): low-bf16 exponent field of x words.
// fp32 data -> ~20% in range; bf16 -> ~100%. Returns 1 if fp32.
__device__ __forceinline__ int block_detect_f32(const unsigned int* __restrict__ xw,
                                                int tid, int* sflag) {
    if (tid < 64) {
        unsigned int u = xw[tid];
        unsigned int e = (u >> 7) & 0xFFu;
        unsigned long long m = __ballot(e >= 100u && e <= 150u);
        if (tid == 0) *sflag = (__popcll(m) < 48) ? 1 : 0;
    }
    __syncthreads();
    return *sflag;
}

// ------------------------------------------------------------------
// LDS-tiled W transpose: Wt[w*64+n][k] = W_w[k][n], bf16.
// grid 48 = 3 w * 16 k-tiles of 64.
// ------------------------------------------------------------------
__global__ __launch_bounds__(256) void transpose_w_kernel(
    const void* __restrict__ Wq, const void* __restrict__ Wk,
    const void* __restrict__ Wv, const unsigned int* __restrict__ xw,
    unsigned short* __restrict__ Wt) {
    __shared__ int sflag;
    __shared__ unsigned short ts[64][68];
    const int tid = threadIdx.x;
    const int isf32 = block_detect_f32(xw, tid, &sflag);
    const int w = blockIdx.x >> 4, kt = blockIdx.x & 15;
    const void* W = (w == 0) ? Wq : (w == 1) ? Wk : Wv;
    const int kk = tid >> 4, nn = (tid & 15) * 4;
#pragma unroll
    for (int j = 0; j < 4; ++j) {
        int k = kk + j * 16;
        if (isf32) {
            float4 f = *(const float4*)((const float*)W + (size_t)(kt * 64 + k) * 64 + nn);
            ts[k][nn + 0] = f2bf(f.x); ts[k][nn + 1] = f2bf(f.y);
            ts[k][nn + 2] = f2bf(f.z); ts[k][nn + 3] = f2bf(f.w);
        } else {
            *(uint2*)&ts[k][nn] =
                *(const uint2*)((const unsigned short*)W + (size_t)(kt * 64 + k) * 64 + nn);
        }
    }
    __syncthreads();
    const int n = tid >> 2, k0 = (tid & 3) * 16;
    unsigned short tmp[16];
#pragma unroll
    for (int j = 0; j < 16; ++j) tmp[j] = ts[k0 + j][n];
    unsigned short* dst = Wt + (size_t)(w * 64 + n) * 1024 + kt * 64 + k0;
    *(uint4*)(dst + 0) = *(uint4*)&tmp[0];
    *(uint4*)(dst + 8) = *(uint4*)&tmp[8];
}

// ------------------------------------------------------------------
// Fused QKV projection: x read ONCE. grid 512 (M-tile 32), 256 thr.
// Wave = 16 rows x 96 cols (6 col-tiles of the 192-wide fused N dim).
// ------------------------------------------------------------------
__global__ __launch_bounds__(256) void proj_kernel(
    const void* __restrict__ xraw, const unsigned short* __restrict__ Wt,
    unsigned short* __restrict__ qbuf, unsigned short* __restrict__ kbuf,
    unsigned short* __restrict__ vtbuf) {
    __shared__ int sflag;
    __shared__ __align__(16) unsigned short xs[32][72];
    __shared__ __align__(16) unsigned short wts[192][72];

    const int tid = threadIdx.x;
    const int isf32 = block_detect_f32((const unsigned int*)xraw, tid, &sflag);
    const int m0 = blockIdx.x * 32;
    const int wave = tid >> 6, lane = tid & 63, quad = lane >> 4, l15 = lane & 15;
    const int rw = wave & 1, cw = wave >> 1;

    f32x4 acc[6];
#pragma unroll
    for (int c = 0; c < 6; ++c) acc[c] = (f32x4){0.f, 0.f, 0.f, 0.f};

    const float* xf = (const float*)xraw;
    const unsigned short* xb = (const unsigned short*)xraw;
    const int xr = tid >> 3, xc = (tid & 7) * 8;

    for (int k0 = 0; k0 < DIN; k0 += 64) {
        if (isf32) {
            const float* gp = xf + (size_t)(m0 + xr) * DIN + k0 + xc;
            float4 f0 = *(const float4*)(gp + 0);
            float4 f1 = *(const float4*)(gp + 4);
            unsigned short t[8] = {f2bf(f0.x), f2bf(f0.y), f2bf(f0.z), f2bf(f0.w),
                                   f2bf(f1.x), f2bf(f1.y), f2bf(f1.z), f2bf(f1.w)};
            *(uint4*)&xs[xr][xc] = *(uint4*)t;
        } else {
            *(uint4*)&xs[xr][xc] =
                *(const uint4*)(xb + (size_t)(m0 + xr) * DIN + k0 + xc);
        }
#pragma unroll
        for (int j = 0; j < 6; ++j) {
            int u = tid + j * 256;
            int n = u >> 3, cc = (u & 7) * 8;
            *(uint4*)&wts[n][cc] = *(const uint4*)(Wt + (size_t)n * 1024 + k0 + cc);
        }
        __syncthreads();
#pragma unroll
        for (int ks = 0; ks < 2; ++ks) {
            bf16x8 a = *(const bf16x8*)&xs[rw * 16 + l15][ks * 32 + quad * 8];
#pragma unroll
            for (int c = 0; c < 6; ++c) {
                bf16x8 bb = *(const bf16x8*)&wts[(cw * 6 + c) * 16 + l15][ks * 32 + quad * 8];
                acc[c] = __builtin_amdgcn_mfma_f32_16x16x32_bf16(a, bb, acc[c], 0, 0, 0);
            }
        }
        __syncthreads();
    }

#pragma unroll
    for (int c = 0; c < 6; ++c) {
        int cg = cw * 6 + c;
        int wsel = cg >> 2;
        int nn = (cg & 3) * 16 + l15;
#pragma unroll
        for (int reg = 0; reg < 4; ++reg) {
            int m = m0 + rw * 16 + quad * 4 + reg;
            unsigned short bv = f2bf(acc[c][reg]);
            if (wsel == 0)      qbuf[(size_t)m * HH + nn] = bv;
            else if (wsel == 1) kbuf[(size_t)m * HH + nn] = bv;
            else {
                int bb = m >> 11, t = m & 2047;
                vtbuf[((size_t)bb * HH + nn) * TT + t] = bv;
            }
        }
    }
}

// ------------------------------------------------------------------
// Split-column flash attention, FIXED exponent shift (no online max;
// partials are directly summable). Block = (row-tile rt, chunk ch of
// up to 8 col-tiles). grid (80, 8). Writes partial O(fp32) + l to ws.
// ------------------------------------------------------------------
__global__ __launch_bounds__(256) void attn_kernel(
    const unsigned short* __restrict__ rowbuf,  // k-proj [b][t][h]
    const unsigned short* __restrict__ colbuf,  // q-proj [b][s][h]
    const unsigned short* __restrict__ vtbuf,   // [b][h][s]
    float* __restrict__ O_part,                 // [slot][64][64]
    float* __restrict__ l_part) {               // [slot][64]

    __shared__ __align__(16) unsigned short Qr_s[64][72];
    __shared__ __align__(16) unsigned short Kc_s[64][72];
    __shared__ __align__(16) unsigned short Vt_s[64][72];
    __shared__ __align__(16) unsigned short P_s[4][16][72];

    const int tid  = threadIdx.x;
    const int bx   = blockIdx.x;   // 0..79
    const int b    = blockIdx.y;
    int rt, ch;
    if (bx < 8)       { rt = bx;                 ch = 0; }
    else if (bx < 24) { rt = 8 + ((bx - 8) >> 1);  ch = (bx - 8) & 1; }
    else if (bx < 48) { rt = 16 + (bx - 24) / 3;   ch = (bx - 24) % 3; }
    else              { rt = 24 + ((bx - 48) >> 2); ch = (bx - 48) & 3; }
    const int nct = min(8, rt + 1 - ch * 8);
    const int t0 = rt * 64;
    const int slot = b * 80 + bx;

    const int wave = tid >> 6, lane = tid & 63, quad = lane >> 4, l15 = lane & 15;
    const int sr = tid >> 2, sc = (tid & 3) * 16;

    {
        const uint4* g = (const uint4*)(rowbuf + ((size_t)b * TT + t0 + sr) * HH + sc);
        *(uint4*)&Qr_s[sr][sc + 0] = g[0];
        *(uint4*)&Qr_s[sr][sc + 8] = g[1];
    }

    f32x4 o[4];
#pragma unroll
    for (int c = 0; c < 4; ++c) o[c] = (f32x4){0.f, 0.f, 0.f, 0.f};
    float ls[4] = {0.f, 0.f, 0.f, 0.f};

    const float SCL2 = 0.125f * 1.4426950408889634f;  // H^-0.5 * log2(e)

    for (int i = 0; i < nct; ++i) {
        const int stc = ch * 8 + i;
        const int s0 = stc * 64;
        {
            const uint4* gk = (const uint4*)(colbuf + ((size_t)b * TT + s0 + sr) * HH + sc);
            uint4 k0 = gk[0], k1 = gk[1];
            const uint4* gv = (const uint4*)(vtbuf + ((size_t)b * HH + sr) * TT + s0 + sc);
            uint4 v0 = gv[0], v1 = gv[1];
            *(uint4*)&Kc_s[sr][sc + 0] = k0;
            *(uint4*)&Kc_s[sr][sc + 8] = k1;
            *(uint4*)&Vt_s[sr][sc + 0] = v0;
            *(uint4*)&Vt_s[sr][sc + 8] = v1;
        }
        __syncthreads();

        f32x4 scf[4];
#pragma unroll
        for (int c = 0; c < 4; ++c) scf[c] = (f32x4){0.f, 0.f, 0.f, 0.f};
#pragma unroll
        for (int ks = 0; ks < 2; ++ks) {
            bf16x8 a = *(const bf16x8*)&Qr_s[wave * 16 + l15][ks * 32 + quad * 8];
#pragma unroll
            for (int c = 0; c < 4; ++c) {
                bf16x8 bb = *(const bf16x8*)&Kc_s[c * 16 + l15][ks * 32 + quad * 8];
                scf[c] = __builtin_amdgcn_mfma_f32_16x16x32_bf16(a, bb, scf[c], 0, 0, 0);
            }
        }

        const bool diag = (stc == rt);
#pragma unroll
        for (int r = 0; r < 4; ++r) {
            const int tg = t0 + wave * 16 + quad * 4 + r;
#pragma unroll
            for (int c = 0; c < 4; ++c) {
                float arg = fmaf(scf[c][r], SCL2, -30.f);
                if (diag && (s0 + c * 16 + l15) > tg) arg = -200.f;
                float p = __builtin_amdgcn_exp2f(arg);
                P_s[wave][quad * 4 + r][c * 16 + l15] = f2bf(p);
                ls[r] += p;
            }
        }
        // P_s is per-wave: intra-wave LDS RAW, compiler lgkmcnt suffices.
#pragma unroll
        for (int ks = 0; ks < 2; ++ks) {
            bf16x8 ap = *(const bf16x8*)&P_s[wave][l15][ks * 32 + quad * 8];
#pragma unroll
            for (int c = 0; c < 4; ++c) {
                bf16x8 bv = *(const bf16x8*)&Vt_s[c * 16 + l15][ks * 32 + quad * 8];
                o[c] = __builtin_amdgcn_mfma_f32_16x16x32_bf16(ap, bv, o[c], 0, 0, 0);
            }
        }
        __syncthreads();   // Kc/Vt consumed; safe to restage
    }

    // per-row l: reduce over the 16 l15 lanes (once, at the end)
#pragma unroll
    for (int r = 0; r < 4; ++r) {
#pragma unroll
        for (int off = 1; off < 16; off <<= 1) ls[r] += __shfl_xor(ls[r], off);
    }
    if (l15 == 0) {
#pragma unroll
        for (int r = 0; r < 4; ++r)
            l_part[(size_t)slot * 64 + wave * 16 + quad * 4 + r] = ls[r];
    }
#pragma unroll
    for (int c = 0; c < 4; ++c)
#pragma unroll
        for (int r = 0; r < 4; ++r)
            O_part[(size_t)slot * 4096 + (wave * 16 + quad * 4 + r) * 64 + c * 16 + l15] = o[c][r];
}

// ------------------------------------------------------------------
// Combine partials: out = (sum O_part) / (sum l_part). grid (32, 8).
// ------------------------------------------------------------------
__global__ __launch_bounds__(256) void combine_kernel(
    const float* __restrict__ O_part, const float* __restrict__ l_part,
    const unsigned int* __restrict__ xw, void* __restrict__ outraw) {
    __shared__ int sflag;
    const int tid = threadIdx.x;
    const int isf32 = block_detect_f32(xw, tid, &sflag);
    const int rt = blockIdx.x, b = blockIdx.y;
    const int nch = rt / 8 + 1;
    const int off = (rt < 8) ? rt : (rt < 16) ? 8 + 2 * (rt - 8)
                   : (rt < 24) ? 24 + 3 * (rt - 16) : 48 + 4 * (rt - 24);
    const int slot0 = b * 80 + off;

    const int row = tid >> 2, cb = (tid & 3) * 16;
    f32x4 a[4];
#pragma unroll
    for (int q = 0; q < 4; ++q) a[q] = (f32x4){0.f, 0.f, 0.f, 0.f};
    float l = 0.f;
    for (int j = 0; j < nch; ++j) {
        const f32x4* p = (const f32x4*)(O_part + (size_t)(slot0 + j) * 4096 + row * 64 + cb);
#pragma unroll
        for (int q = 0; q < 4; ++q) a[q] += p[q];
        l += l_part[(size_t)(slot0 + j) * 64 + row];
    }
    const float inv = 1.f / l;
    const size_t base = ((size_t)b * TT + rt * 64 + row) * HH + cb;
    if (isf32) {
        float* outf = (float*)outraw;
#pragma unroll
        for (int q = 0; q < 4; ++q) {
            f32x4 v = a[q] * inv;
            *(f32x4*)(outf + base + q * 4) = v;
        }
    } else {
        unsigned short h[16];
#pragma unroll
        for (int q = 0; q < 4; ++q)
#pragma unroll
            for (int e = 0; e < 4; ++e) h[q * 4 + e] = f2bf(a[q][e] * inv);
        unsigned short* outb = (unsigned short*)outraw;
        *(uint4*)(outb + base + 0) = *(uint4*)&h[0];
        *(uint4*)(outb + base + 8) = *(uint4*)&h[8];
    }
}

extern "C" void kernel_launch(void* const* d_in, const int* in_sizes, int n_in,
                              void* d_out, int out_size, void* d_ws, size_t ws_size,
                              hipStream_t stream) {
    const void* x  = d_in[0];
    const void* Wq = d_in[1];
    const void* Wk = d_in[2];
    const void* Wv = d_in[3];
    unsigned short* ws = (unsigned short*)d_ws;

    unsigned short* qbuf  = ws;                          // 2 MB
    unsigned short* kbuf  = ws + (size_t)MM * HH;        // 2 MB
    unsigned short* vtbuf = ws + (size_t)2 * MM * HH;    // 2 MB
    unsigned short* wtbuf = ws + (size_t)3 * MM * HH;    // 384 KB
    float* O_part = (float*)(ws + (size_t)3 * MM * HH + 3 * 65536);  // 10.5 MB
    float* l_part = O_part + (size_t)640 * 4096;                      // 164 KB

    hipLaunchKernelGGL(transpose_w_kernel, dim3(48), dim3(256), 0, stream,
                       Wq, Wk, Wv, (const unsigned int*)x, wtbuf);
    hipLaunchKernelGGL(proj_kernel, dim3(512), dim3(256), 0, stream,
                       x, wtbuf, qbuf, kbuf, vtbuf);
    hipLaunchKernelGGL(attn_kernel, dim3(80, 8), dim3(256), 0, stream,
                       kbuf, qbuf, vtbuf, O_part, l_part);
    hipLaunchKernelGGL(combine_kernel, dim3(32, 8), dim3(256), 0, stream,
                       O_part, l_part, (const unsigned int*)x, d_out);
}

// Round 4
// 159.579 us; speedup vs baseline: 1.3254x; 1.0043x over previous
//
#include <hip/hip_runtime.h>

typedef __bf16 bf16_t;
typedef bf16_t bf16x8 __attribute__((ext_vector_type(8)));
typedef float f32x4 __attribute__((ext_vector_type(4)));

#define NB 8
#define TT 2048
#define DIN 1024
#define HH 64
#define MM (NB * TT)

__device__ __forceinline__ unsigned short f2bf(float f) {
    unsigned int u = __float_as_uint(f);
    u += 0x7fffu + ((u >> 16) & 1u);   // round-to-nearest-even
    return (unsigned short)(u >> 16);
}

// Per-block dtype probe: low-bf16 exponent field of x words.
// fp32 data -> ~20% in range; bf16 -> ~100%. Returns 1 if fp32.
__device__ __forceinline__ int block_detect_f32(const unsigned int* __restrict__ xw,
                                                int tid, int* sflag) {
    if (tid < 64) {
        unsigned int u = xw[tid];
        unsigned int e = (u >> 7) & 0xFFu;
        unsigned long long m = __ballot(e >= 100u && e <= 150u);
        if (tid == 0) *sflag = (__popcll(m) < 48) ? 1 : 0;
    }
    __syncthreads();
    return *sflag;
}

// ------------------------------------------------------------------
// LDS-tiled W transpose: Wt[w*64+n][k] = W_w[k][n], bf16.
// grid 48 = 3 w * 16 k-tiles of 64.
// ------------------------------------------------------------------
__global__ __launch_bounds__(256) void transpose_w_kernel(
    const void* __restrict__ Wq, const void* __restrict__ Wk,
    const void* __restrict__ Wv, const unsigned int* __restrict__ xw,
    unsigned short* __restrict__ Wt) {
    __shared__ int sflag;
    __shared__ unsigned short ts[64][68];
    const int tid = threadIdx.x;
    const int isf32 = block_detect_f32(xw, tid, &sflag);
    const int w = blockIdx.x >> 4, kt = blockIdx.x & 15;
    const void* W = (w == 0) ? Wq : (w == 1) ? Wk : Wv;
    const int kk = tid >> 4, nn = (tid & 15) * 4;
#pragma unroll
    for (int j = 0; j < 4; ++j) {
        int k = kk + j * 16;
        if (isf32) {
            float4 f = *(const float4*)((const float*)W + (size_t)(kt * 64 + k) * 64 + nn);
            ts[k][nn + 0] = f2bf(f.x); ts[k][nn + 1] = f2bf(f.y);
            ts[k][nn + 2] = f2bf(f.z); ts[k][nn + 3] = f2bf(f.w);
        } else {
            *(uint2*)&ts[k][nn] =
                *(const uint2*)((const unsigned short*)W + (size_t)(kt * 64 + k) * 64 + nn);
        }
    }
    __syncthreads();
    const int n = tid >> 2, k0 = (tid & 3) * 16;
    unsigned short tmp[16];
#pragma unroll
    for (int j = 0; j < 16; ++j) tmp[j] = ts[k0 + j][n];
    unsigned short* dst = Wt + (size_t)(w * 64 + n) * 1024 + kt * 64 + k0;
    *(uint4*)(dst + 0) = *(uint4*)&tmp[0];
    *(uint4*)(dst + 8) = *(uint4*)&tmp[8];
}

// ------------------------------------------------------------------
// Fused QKV projection v2: M-tile 64, grid 256 (1 block/CU), N=192,
// BK=64, 16 K-iters, register-prefetch of next iter's x+W tiles.
// Wave tile 32 rows x 96 cols (12 f32x4 acc). HBM-bound by design
// (x fp32 = 67 MB once => ~11 us floor).
// ------------------------------------------------------------------
__global__ __launch_bounds__(256) void proj_kernel(
    const void* __restrict__ xraw, const unsigned short* __restrict__ Wt,
    unsigned short* __restrict__ qbuf, unsigned short* __restrict__ kbuf,
    unsigned short* __restrict__ vtbuf) {
    __shared__ int sflag;
    __shared__ __align__(16) unsigned short xs[64][72];    // +8 pad: 2-way b128 reads
    __shared__ __align__(16) unsigned short wts[192][72];

    const int tid = threadIdx.x;
    const int isf32 = block_detect_f32((const unsigned int*)xraw, tid, &sflag);
    const int m0 = blockIdx.x * 64;
    const int wave = tid >> 6, lane = tid & 63, quad = lane >> 4, l15 = lane & 15;
    const int rw = wave & 1, cw = wave >> 1;   // rows rw*32, cols cw*96

    f32x4 acc[2][6];
#pragma unroll
    for (int rt = 0; rt < 2; ++rt)
#pragma unroll
        for (int ct = 0; ct < 6; ++ct)
            acc[rt][ct] = (f32x4){0.f, 0.f, 0.f, 0.f};

    const float* xf = (const float*)xraw;
    const unsigned short* xb = (const unsigned short*)xraw;

    // staging roles
    const int xrow = tid >> 2, xkb = (tid & 3) * 16;   // 16 x-elems / thread
    // W: 1536 16B-chunks, 6 per thread

    float4 px[4];          // fp32 x prefetch
    uint4  pxb[2];         // bf16 x prefetch
    uint4  pw[6];          // W prefetch

    auto prefetch = [&](int k0) {
        if (isf32) {
            const float* gp = xf + (size_t)(m0 + xrow) * DIN + k0 + xkb;
#pragma unroll
            for (int j = 0; j < 4; ++j) px[j] = *(const float4*)(gp + j * 4);
        } else {
            const unsigned short* gp = xb + (size_t)(m0 + xrow) * DIN + k0 + xkb;
            pxb[0] = *(const uint4*)(gp + 0);
            pxb[1] = *(const uint4*)(gp + 8);
        }
#pragma unroll
        for (int j = 0; j < 6; ++j) {
            int c = tid + j * 256;
            int row = c >> 3, kc = c & 7;
            pw[j] = *(const uint4*)(Wt + (size_t)row * 1024 + k0 + kc * 8);
        }
    };

    prefetch(0);

    for (int it = 0; it < 16; ++it) {
        __syncthreads();   // prev compute done; LDS reusable
        if (isf32) {
            unsigned short t[16];
#pragma unroll
            for (int j = 0; j < 4; ++j) {
                t[j * 4 + 0] = f2bf(px[j].x); t[j * 4 + 1] = f2bf(px[j].y);
                t[j * 4 + 2] = f2bf(px[j].z); t[j * 4 + 3] = f2bf(px[j].w);
            }
            *(uint4*)&xs[xrow][xkb + 0] = *(uint4*)&t[0];
            *(uint4*)&xs[xrow][xkb + 8] = *(uint4*)&t[8];
        } else {
            *(uint4*)&xs[xrow][xkb + 0] = pxb[0];
            *(uint4*)&xs[xrow][xkb + 8] = pxb[1];
        }
#pragma unroll
        for (int j = 0; j < 6; ++j) {
            int c = tid + j * 256;
            int row = c >> 3, kc = c & 7;
            *(uint4*)&wts[row][kc * 8] = pw[j];
        }
        __syncthreads();

        if (it < 15) prefetch((it + 1) * 64);

#pragma unroll
        for (int ks = 0; ks < 2; ++ks) {
            bf16x8 a[2], b[6];
#pragma unroll
            for (int rt = 0; rt < 2; ++rt)
                a[rt] = *(const bf16x8*)&xs[rw * 32 + rt * 16 + l15][ks * 32 + quad * 8];
#pragma unroll
            for (int ct = 0; ct < 6; ++ct)
                b[ct] = *(const bf16x8*)&wts[cw * 96 + ct * 16 + l15][ks * 32 + quad * 8];
#pragma unroll
            for (int rt = 0; rt < 2; ++rt)
#pragma unroll
                for (int ct = 0; ct < 6; ++ct)
                    acc[rt][ct] = __builtin_amdgcn_mfma_f32_16x16x32_bf16(
                        a[rt], b[ct], acc[rt][ct], 0, 0, 0);
        }
    }

    // epilogue: D[row=quad*4+reg][col=l15]
#pragma unroll
    for (int rt = 0; rt < 2; ++rt)
#pragma unroll
        for (int ct = 0; ct < 6; ++ct) {
            int n = cw * 96 + ct * 16 + l15;
            int wsel = n >> 6, nn = n & 63;
#pragma unroll
            for (int reg = 0; reg < 4; ++reg) {
                int m = m0 + rw * 32 + rt * 16 + quad * 4 + reg;
                unsigned short bv = f2bf(acc[rt][ct][reg]);
                if (wsel == 0)      qbuf[(size_t)m * HH + nn] = bv;
                else if (wsel == 1) kbuf[(size_t)m * HH + nn] = bv;
                else {
                    int bb = m >> 11, t = m & 2047;
                    vtbuf[((size_t)bb * HH + nn) * TT + t] = bv;
                }
            }
        }
}

// ------------------------------------------------------------------
// Split-column flash attention, FIXED exponent shift (no online max;
// partials are directly summable). Block = (row-tile rt, chunk ch of
// up to 8 col-tiles). grid (80, 8). Writes partial O(fp32) + l to ws.
// ------------------------------------------------------------------
__global__ __launch_bounds__(256) void attn_kernel(
    const unsigned short* __restrict__ rowbuf,  // k-proj [b][t][h]
    const unsigned short* __restrict__ colbuf,  // q-proj [b][s][h]
    const unsigned short* __restrict__ vtbuf,   // [b][h][s]
    float* __restrict__ O_part,                 // [slot][64][64]
    float* __restrict__ l_part) {               // [slot][64]

    __shared__ __align__(16) unsigned short Qr_s[64][72];
    __shared__ __align__(16) unsigned short Kc_s[64][72];
    __shared__ __align__(16) unsigned short Vt_s[64][72];
    __shared__ __align__(16) unsigned short P_s[4][16][72];

    const int tid  = threadIdx.x;
    const int bx   = blockIdx.x;   // 0..79
    const int b    = blockIdx.y;
    int rt, ch;
    if (bx < 8)       { rt = bx;                 ch = 0; }
    else if (bx < 24) { rt = 8 + ((bx - 8) >> 1);  ch = (bx - 8) & 1; }
    else if (bx < 48) { rt = 16 + (bx - 24) / 3;   ch = (bx - 24) % 3; }
    else              { rt = 24 + ((bx - 48) >> 2); ch = (bx - 48) & 3; }
    const int nct = min(8, rt + 1 - ch * 8);
    const int t0 = rt * 64;
    const int slot = b * 80 + bx;

    const int wave = tid >> 6, lane = tid & 63, quad = lane >> 4, l15 = lane & 15;
    const int sr = tid >> 2, sc = (tid & 3) * 16;

    {
        const uint4* g = (const uint4*)(rowbuf + ((size_t)b * TT + t0 + sr) * HH + sc);
        *(uint4*)&Qr_s[sr][sc + 0] = g[0];
        *(uint4*)&Qr_s[sr][sc + 8] = g[1];
    }

    f32x4 o[4];
#pragma unroll
    for (int c = 0; c < 4; ++c) o[c] = (f32x4){0.f, 0.f, 0.f, 0.f};
    float ls[4] = {0.f, 0.f, 0.f, 0.f};

    const float SCL2 = 0.125f * 1.4426950408889634f;  // H^-0.5 * log2(e)

    for (int i = 0; i < nct; ++i) {
        const int stc = ch * 8 + i;
        const int s0 = stc * 64;
        {
            const uint4* gk = (const uint4*)(colbuf + ((size_t)b * TT + s0 + sr) * HH + sc);
            uint4 k0 = gk[0], k1 = gk[1];
            const uint4* gv = (const uint4*)(vtbuf + ((size_t)b * HH + sr) * TT + s0 + sc);
            uint4 v0 = gv[0], v1 = gv[1];
            *(uint4*)&Kc_s[sr][sc + 0] = k0;
            *(uint4*)&Kc_s[sr][sc + 8] = k1;
            *(uint4*)&Vt_s[sr][sc + 0] = v0;
            *(uint4*)&Vt_s[sr][sc + 8] = v1;
        }
        __syncthreads();

        f32x4 scf[4];
#pragma unroll
        for (int c = 0; c < 4; ++c) scf[c] = (f32x4){0.f, 0.f, 0.f, 0.f};
#pragma unroll
        for (int ks = 0; ks < 2; ++ks) {
            bf16x8 a = *(const bf16x8*)&Qr_s[wave * 16 + l15][ks * 32 + quad * 8];
#pragma unroll
            for (int c = 0; c < 4; ++c) {
                bf16x8 bb = *(const bf16x8*)&Kc_s[c * 16 + l15][ks * 32 + quad * 8];
                scf[c] = __builtin_amdgcn_mfma_f32_16x16x32_bf16(a, bb, scf[c], 0, 0, 0);
            }
        }

        const bool diag = (stc == rt);
#pragma unroll
        for (int r = 0; r < 4; ++r) {
            const int tg = t0 + wave * 16 + quad * 4 + r;
#pragma unroll
            for (int c = 0; c < 4; ++c) {
                float arg = fmaf(scf[c][r], SCL2, -30.f);
                if (diag && (s0 + c * 16 + l15) > tg) arg = -200.f;
                float p = __builtin_amdgcn_exp2f(arg);
                P_s[wave][quad * 4 + r][c * 16 + l15] = f2bf(p);
                ls[r] += p;
            }
        }
        // P_s is per-wave: intra-wave LDS RAW, compiler lgkmcnt suffices.
#pragma unroll
        for (int ks = 0; ks < 2; ++ks) {
            bf16x8 ap = *(const bf16x8*)&P_s[wave][l15][ks * 32 + quad * 8];
#pragma unroll
            for (int c = 0; c < 4; ++c) {
                bf16x8 bv = *(const bf16x8*)&Vt_s[c * 16 + l15][ks * 32 + quad * 8];
                o[c] = __builtin_amdgcn_mfma_f32_16x16x32_bf16(ap, bv, o[c], 0, 0, 0);
            }
        }
        __syncthreads();   // Kc/Vt consumed; safe to restage
    }

    // per-row l: reduce over the 16 l15 lanes (once, at the end)
#pragma unroll
    for (int r = 0; r < 4; ++r) {
#pragma unroll
        for (int off = 1; off < 16; off <<= 1) ls[r] += __shfl_xor(ls[r], off);
    }
    if (l15 == 0) {
#pragma unroll
        for (int r = 0; r < 4; ++r)
            l_part[(size_t)slot * 64 + wave * 16 + quad * 4 + r] = ls[r];
    }
#pragma unroll
    for (int c = 0; c < 4; ++c)
#pragma unroll
        for (int r = 0; r < 4; ++r)
            O_part[(size_t)slot * 4096 + (wave * 16 + quad * 4 + r) * 64 + c * 16 + l15] = o[c][r];
}

// ------------------------------------------------------------------
// Combine partials: out = (sum O_part) / (sum l_part). grid (32, 8).
// ------------------------------------------------------------------
__global__ __launch_bounds__(256) void combine_kernel(
    const float* __restrict__ O_part, const float* __restrict__ l_part,
    const unsigned int* __restrict__ xw, void* __restrict__ outraw) {
    __shared__ int sflag;
    const int tid = threadIdx.x;
    const int isf32 = block_detect_f32(xw, tid, &sflag);
    const int rt = blockIdx.x, b = blockIdx.y;
    const int nch = rt / 8 + 1;
    const int off = (rt < 8) ? rt : (rt < 16) ? 8 + 2 * (rt - 8)
                   : (rt < 24) ? 24 + 3 * (rt - 16) : 48 + 4 * (rt - 24);
    const int slot0 = b * 80 + off;

    const int row = tid >> 2, cb = (tid & 3) * 16;
    f32x4 a[4];
#pragma unroll
    for (int q = 0; q < 4; ++q) a[q] = (f32x4){0.f, 0.f, 0.f, 0.f};
    float l = 0.f;
    for (int j = 0; j < nch; ++j) {
        const f32x4* p = (const f32x4*)(O_part + (size_t)(slot0 + j) * 4096 + row * 64 + cb);
#pragma unroll
        for (int q = 0; q < 4; ++q) a[q] += p[q];
        l += l_part[(size_t)(slot0 + j) * 64 + row];
    }
    const float inv = 1.f / l;
    const size_t base = ((size_t)b * TT + rt * 64 + row) * HH + cb;
    if (isf32) {
        float* outf = (float*)outraw;
#pragma unroll
        for (int q = 0; q < 4; ++q) {
            f32x4 v = a[q] * inv;
            *(f32x4*)(outf + base + q * 4) = v;
        }
    } else {
        unsigned short h[16];
#pragma unroll
        for (int q = 0; q < 4; ++q)
#pragma unroll
            for (int e = 0; e < 4; ++e) h[q * 4 + e] = f2bf(a[q][e] * inv);
        unsigned short* outb = (unsigned short*)outraw;
        *(uint4*)(outb + base + 0) = *(uint4*)&h[0];
        *(uint4*)(outb + base + 8) = *(uint4*)&h[8];
    }
}

extern "C" void kernel_launch(void* const* d_in, const int* in_sizes, int n_in,
                              void* d_out, int out_size, void* d_ws, size_t ws_size,
                              hipStream_t stream) {
    const void* x  = d_in[0];
    const void* Wq = d_in[1];
    const void* Wk = d_in[2];
    const void* Wv = d_in[3];
    unsigned short* ws = (unsigned short*)d_ws;

    unsigned short* qbuf  = ws;                          // 2 MB
    unsigned short* kbuf  = ws + (size_t)MM * HH;        // 2 MB
    unsigned short* vtbuf = ws + (size_t)2 * MM * HH;    // 2 MB
    unsigned short* wtbuf = ws + (size_t)3 * MM * HH;    // 384 KB
    float* O_part = (float*)(ws + (size_t)3 * MM * HH + 3 * 65536);  // 10.5 MB
    float* l_part = O_part + (size_t)640 * 4096;                      // 164 KB

    hipLaunchKernelGGL(transpose_w_kernel, dim3(48), dim3(256), 0, stream,
                       Wq, Wk, Wv, (const unsigned int*)x, wtbuf);
    hipLaunchKernelGGL(proj_kernel, dim3(256), dim3(256), 0, stream,
                       x, wtbuf, qbuf, kbuf, vtbuf);
    hipLaunchKernelGGL(attn_kernel, dim3(80, 8), dim3(256), 0, stream,
                       kbuf, qbuf, vtbuf, O_part, l_part);
    hipLaunchKernelGGL(combine_kernel, dim3(32, 8), dim3(256), 0, stream,
                       O_part, l_part, (const unsigned int*)x, d_out);
}